// Round 1
// baseline (868.196 us; speedup 1.0000x reference)
//
#include <hip/hip_runtime.h>

// ProdLayer: out[nids[p]] = sum_j node_mars[cids[p][j]]  (B=128 floats per row)
// Row layout: 128 floats = 32 float4 chunks. 32 threads cooperate per node.
// Memory-bound gather-sum; all accesses are 512B-contiguous wave segments.

#define B4 32  // float4 chunks per row (B=128)

__global__ __launch_bounds__(256) void prod_layer_kernel(
    const float4* __restrict__ nm,      // node_mars, [N_SRC][32] float4
    const float4* __restrict__ em,      // element_mars (input), [N_PROD+1][32] float4
    const int*    __restrict__ nids,    // [N_PROD]
    const int4*   __restrict__ cids,    // [N_PROD] (4 children packed)
    float4*       __restrict__ out,     // [N_PROD+1][32] float4
    int n_prod)
{
    int tid   = blockIdx.x * blockDim.x + threadIdx.x;
    int node  = tid >> 5;          // which output slot group
    int chunk = tid & 31;          // which float4 within the row
    if (node > n_prod) return;

    if (node == 0) {
        // Row 0 is the reserved row, not covered by nids: copy from element_mars.
        out[chunk] = em[chunk];
        return;
    }

    int p = node - 1;
    int4 c = cids[p];              // 32 threads broadcast-load the same int4

    // Four coalesced 512B row-gathers (each: 32 lanes x 16B contiguous)
    float4 a = nm[c.x * B4 + chunk];
    float4 b = nm[c.y * B4 + chunk];
    float4 d = nm[c.z * B4 + chunk];
    float4 e = nm[c.w * B4 + chunk];

    float4 s;
    s.x = (a.x + b.x) + (d.x + e.x);
    s.y = (a.y + b.y) + (d.y + e.y);
    s.z = (a.z + b.z) + (d.z + e.z);
    s.w = (a.w + b.w) + (d.w + e.w);

    out[nids[p] * B4 + chunk] = s;
}

extern "C" void kernel_launch(void* const* d_in, const int* in_sizes, int n_in,
                              void* d_out, int out_size, void* d_ws, size_t ws_size,
                              hipStream_t stream) {
    const float4* nm   = (const float4*)d_in[0];
    const float4* em   = (const float4*)d_in[1];
    const int*    nids = (const int*)d_in[2];
    const int4*   cids = (const int4*)d_in[3];
    float4*       out  = (float4*)d_out;

    const int n_prod = in_sizes[2];              // 500,000
    const long total_threads = (long)(n_prod + 1) * B4;
    const int block = 256;
    const int grid  = (int)((total_threads + block - 1) / block);

    prod_layer_kernel<<<grid, block, 0, stream>>>(nm, em, nids, cids, out, n_prod);
}